// Round 7
// baseline (33.838 us; speedup 1.0000x reference)
//
#include <hip/hip_runtime.h>

#define TPB   512
#define CHUNK 4
#define RPB   (TPB * CHUNK)   // 2048 rows per block
#define NW    (TPB / 64)      // 8 waves

__device__ __forceinline__ float pair_loss(float p0, float s0, float p1, float s1) {
    float dp = p0 - p1;
    float ds = s0 - s1;
    float sg = (ds > 0.0f) ? 1.0f : ((ds < 0.0f) ? -1.0f : 0.0f);
    float t  = dp * sg;
    // stable softplus(-t) = max(-t,0) + log1p(exp(-|t|))
    return fmaxf(-t, 0.0f) + log1pf(__expf(-fabsf(t)));
}

__device__ __forceinline__ void stats_from_regs(float4 a, float4 b, float4 c, float4 d,
                                                float& p, bool& mask) {
    float m01 = fmaxf(fmaxf(a.x, a.y), fmaxf(a.z, a.w));
    float m23 = fmaxf(fmaxf(b.x, b.y), fmaxf(b.z, b.w));
    float m45 = fmaxf(fmaxf(c.x, c.y), fmaxf(c.z, c.w));
    float m67 = fmaxf(fmaxf(d.x, d.y), fmaxf(d.z, d.w));
    float m = fmaxf(fmaxf(m01, m23), fmaxf(m45, m67));
    float sum = __expf(a.x - m) + __expf(a.y - m) + __expf(a.z - m) + __expf(a.w - m)
              + __expf(b.x - m) + __expf(b.y - m) + __expf(b.z - m) + __expf(b.w - m)
              + __expf(c.x - m) + __expf(c.y - m) + __expf(c.z - m) + __expf(c.w - m)
              + __expf(d.x - m) + __expf(d.y - m) + __expf(d.z - m) + __expf(d.w - m);
    p = __builtin_amdgcn_rcpf(sum);   // ~1ulp; tolerance is huge
    mask = (a.x == m);
}

__device__ __forceinline__ void load_row(const float* __restrict__ outp,
                                         const float* __restrict__ score,
                                         int row, int B,
                                         float4& a, float4& b, float4& c, float4& d,
                                         float& s) {
    if (row < B) {
        const float4* o4 = (const float4*)outp + (size_t)row * 4;
        a = o4[0]; b = o4[1]; c = o4[2]; d = o4[3];
        s = score[row];
    } else {
        a = b = c = d = make_float4(0.f, 0.f, 0.f, 0.f);
        s = 0.f;
    }
}

// k1: CHUNK tiles of 512 rows per block; register-prefetch pipeline; in-register
// cross-tile carry in thread 0; one forward boundary scan per block.
__global__ void __launch_bounds__(TPB) k_fused(const float* __restrict__ outp,
                                               const float* __restrict__ score,
                                               float* __restrict__ bpart, int B) {
    __shared__ float sp[2][TPB];
    __shared__ float ss[2][TPB];
    __shared__ unsigned long long wmask[2][NW];
    __shared__ float wsum[NW];

    int tid  = threadIdx.x;
    int lane = tid & 63;
    int wid  = tid >> 6;
    int blk0 = blockIdx.x * RPB;

    float acc = 0.0f;
    float cp = 0.0f, cs = 0.0f;   // carry: last selected so far (thread 0 only)
    int   cvalid = 0;

    float4 a0, b0, c0, d0, a1, b1, c1, d1;
    float  s0, s1;
    load_row(outp, score, blk0 + tid, B, a0, b0, c0, d0, s0);

#pragma unroll
    for (int t = 0; t < CHUNK; ++t) {
        // prefetch next tile (global loads overlap this tile's LDS/compute)
        if (t + 1 < CHUNK)
            load_row(outp, score, blk0 + (t + 1) * TPB + tid, B, a1, b1, c1, d1, s1);

        float p; bool mask;
        stats_from_regs(a0, b0, c0, d0, p, mask);
        if (blk0 + t * TPB + tid >= B) mask = false;

        int buf = t & 1;
        sp[buf][tid] = p;
        ss[buf][tid] = s0;
        unsigned long long bal = __ballot(mask);
        if (lane == 0) wmask[buf][wid] = bal;
        __syncthreads();   // also protects reuse of buf from tile t-2

        // block-local pair: my selected row -> next selected row in this tile
        if (mask) {
            unsigned long long above = bal & ~((2ull << lane) - 1ull); // lane63 -> 0
            int nxt = -1;
            if (above) {
                nxt = (wid << 6) + __ffsll(above) - 1;
            } else {
                for (int w = wid + 1; w < NW; ++w)
                    if (wmask[buf][w]) { nxt = (w << 6) + __ffsll(wmask[buf][w]) - 1; break; }
            }
            if (nxt >= 0) acc += pair_loss(p, s0, sp[buf][nxt], ss[buf][nxt]);
        }

        // thread 0: cross-tile link via carried last-selected
        if (tid == 0) {
            int first = -1, last = -1;
            for (int w = 0; w < NW; ++w)
                if (wmask[buf][w]) { first = (w << 6) + __ffsll(wmask[buf][w]) - 1; break; }
            for (int w = NW - 1; w >= 0; --w)
                if (wmask[buf][w]) { last = (w << 6) + 63 - __clzll(wmask[buf][w]); break; }
            if (first >= 0) {
                if (cvalid)
                    acc += pair_loss(cp, cs, sp[buf][first], ss[buf][first]);
                cp = sp[buf][last];
                cs = ss[buf][last];
                cvalid = 1;
            }
        }

        // rotate pipeline regs
        a0 = a1; b0 = b1; c0 = c1; d0 = d1; s0 = s1;
    }

    // wave 0: cross-block pair via forward scan (carry broadcast from lane 0)
    if (wid == 0) {
        int   v  = __shfl(cvalid, 0);
        float pl = __shfl(cp, 0);
        float sl = __shfl(cs, 0);
        if (v) {
            int base = blk0 + RPB;
            while (base < B) {
                int r = base + lane;
                bool sel = false;
                float pf = 0.0f, sf = 0.0f;
                if (r < B) {
                    float4 a, b, c, d; float sc;
                    load_row(outp, score, r, B, a, b, c, d, sc);
                    stats_from_regs(a, b, c, d, pf, sel);
                    sf = sc;
                }
                unsigned long long b2 = __ballot(sel);
                if (b2) {
                    int fl = __ffsll(b2) - 1;
                    float pfirst = __shfl(pf, fl);
                    float sfirst = __shfl(sf, fl);
                    if (lane == 0) acc += pair_loss(pl, sl, pfirst, sfirst);
                    break;
                }
                base += 64;
            }
        }
    }

    // block reduce -> contention-free partial write
    for (int off = 32; off > 0; off >>= 1) acc += __shfl_down(acc, off);
    if (lane == 0) wsum[wid] = acc;
    __syncthreads();
    if (tid == 0) {
        float t = 0.0f;
        for (int w = 0; w < NW; ++w) t += wsum[w];
        bpart[blockIdx.x] = t;
    }
}

// k2: single block sums the per-block partials, writes out[0].
__global__ void k2_sum(const float* __restrict__ bpart, int nb,
                       float* __restrict__ out) {
    __shared__ float wsum[8];
    float acc = 0.0f;
    for (int b = threadIdx.x; b < nb; b += 512) acc += bpart[b];
    int lane = threadIdx.x & 63;
    int wid  = threadIdx.x >> 6;
    for (int off = 32; off > 0; off >>= 1) acc += __shfl_down(acc, off);
    if (lane == 0) wsum[wid] = acc;
    __syncthreads();
    if (threadIdx.x == 0) {
        float t = 0.0f;
        for (int w = 0; w < 8; ++w) t += wsum[w];
        out[0] = t;
    }
}

extern "C" void kernel_launch(void* const* d_in, const int* in_sizes, int n_in,
                              void* d_out, int out_size, void* d_ws, size_t ws_size,
                              hipStream_t stream) {
    const float* outp  = (const float*)d_in[0];   // [B,16] logits
    const float* score = (const float*)d_in[1];   // [B]
    float* out = (float*)d_out;

    int B  = in_sizes[1];
    int nb = (B + RPB - 1) / RPB;

    float* bpart = (float*)d_ws;

    k_fused<<<nb, TPB, 0, stream>>>(outp, score, bpart, B);
    k2_sum<<<1, 512, 0, stream>>>(bpart, nb, out);
}

// Round 8
// 32.148 us; speedup vs baseline: 1.0526x; 1.0526x over previous
//
#include <hip/hip_runtime.h>

#define TPB 1024
#define NW  (TPB / 64)   // 16 waves per block

__device__ __forceinline__ float pair_loss(float p0, float s0, float p1, float s1) {
    float dp = p0 - p1;
    float ds = s0 - s1;
    float sg = (ds > 0.0f) ? 1.0f : ((ds < 0.0f) ? -1.0f : 0.0f);
    float t  = dp * sg;
    // stable softplus(-t) = max(-t,0) + log1p(exp(-|t|))
    return fmaxf(-t, 0.0f) + log1pf(__expf(-fabsf(t)));
}

// Row's top softmax prob p and mask (argmax==0) from 16 logits.
__device__ __forceinline__ void row_stats(const float* __restrict__ outp, int row,
                                          float& p, bool& mask) {
    const float4* o4 = (const float4*)outp + (size_t)row * 4;
    float4 a = o4[0];
    float4 b = o4[1];
    float4 c = o4[2];
    float4 d = o4[3];
    float m01 = fmaxf(fmaxf(a.x, a.y), fmaxf(a.z, a.w));
    float m23 = fmaxf(fmaxf(b.x, b.y), fmaxf(b.z, b.w));
    float m45 = fmaxf(fmaxf(c.x, c.y), fmaxf(c.z, c.w));
    float m67 = fmaxf(fmaxf(d.x, d.y), fmaxf(d.z, d.w));
    float m = fmaxf(fmaxf(m01, m23), fmaxf(m45, m67));
    float sum = __expf(a.x - m) + __expf(a.y - m) + __expf(a.z - m) + __expf(a.w - m)
              + __expf(b.x - m) + __expf(b.y - m) + __expf(b.z - m) + __expf(b.w - m)
              + __expf(c.x - m) + __expf(c.y - m) + __expf(c.z - m) + __expf(c.w - m)
              + __expf(d.x - m) + __expf(d.y - m) + __expf(d.z - m) + __expf(d.w - m);
    p = __builtin_amdgcn_rcpf(sum);   // ~1ulp approx; tolerance is huge
    mask = (a.x == m);
}

// k1: 1 row/thread, 1024-thread blocks. Block-local adjacent-selected pairs +
//     own cross-boundary pair via forward scan; per-block partial (no atomics).
__global__ void __launch_bounds__(TPB) k_fused(const float* __restrict__ outp,
                                               const float* __restrict__ score,
                                               float* __restrict__ bpart, int B) {
    __shared__ float sp[TPB];
    __shared__ float ss[TPB];
    __shared__ unsigned long long wmask[NW];
    __shared__ float wsum[NW];

    int tid  = threadIdx.x;
    int lane = tid & 63;
    int wid  = tid >> 6;
    int row  = blockIdx.x * TPB + tid;

    bool mask = false;
    float p = 0.0f, s = 0.0f;
    if (row < B) {
        row_stats(outp, row, p, mask);
        s = score[row];                // coalesced
    }
    sp[tid] = p;
    ss[tid] = s;

    unsigned long long bal = __ballot(mask);
    if (lane == 0) wmask[wid] = bal;
    __syncthreads();

    float acc = 0.0f;
    if (mask) {
        // next selected thread index within this block
        unsigned long long above = bal & ~((2ull << lane) - 1ull); // lane 63: (2<<63)==0 -> above=0
        int nxt = -1;
        if (above) {
            nxt = (wid << 6) + __ffsll(above) - 1;
        } else {
            for (int w = wid + 1; w < NW; ++w)
                if (wmask[w]) { nxt = (w << 6) + __ffsll(wmask[w]) - 1; break; }
        }
        if (nxt >= 0) acc = pair_loss(p, s, sp[nxt], ss[nxt]);
    }

    // wave 0: cross-boundary pair via forward scan into following rows
    // (runs concurrently with other waves' pair loop above)
    if (wid == 0) {
        int last = -1;
        for (int w = NW - 1; w >= 0; --w)
            if (wmask[w]) { last = (w << 6) + 63 - __clzll(wmask[w]); break; }
        if (last >= 0) {
            float pl = sp[last];
            float sl = ss[last];
            int base = (blockIdx.x + 1) * TPB;
            while (base < B) {
                int r = base + lane;
                bool sel = false;
                float pf = 0.0f, sf = 0.0f;
                if (r < B) {
                    row_stats(outp, r, pf, sel);
                    sf = score[r];
                }
                unsigned long long b2 = __ballot(sel);
                if (b2) {
                    int fl = __ffsll(b2) - 1;
                    float pfirst = __shfl(pf, fl);
                    float sfirst = __shfl(sf, fl);
                    if (lane == 0) acc += pair_loss(pl, sl, pfirst, sfirst);
                    break;
                }
                base += 64;
            }
        }
    }

    // block reduce -> contention-free partial write
    for (int off = 32; off > 0; off >>= 1) acc += __shfl_down(acc, off);
    if (lane == 0) wsum[wid] = acc;
    __syncthreads();
    if (tid == 0) {
        float t = 0.0f;
        for (int w = 0; w < NW; ++w) t += wsum[w];
        bpart[blockIdx.x] = t;
    }
}

// k2: single block sums the per-block partials, writes out[0].
__global__ void k2_sum(const float* __restrict__ bpart, int nb,
                       float* __restrict__ out) {
    __shared__ float wsum[16];
    float acc = 0.0f;
    for (int b = threadIdx.x; b < nb; b += 1024) acc += bpart[b];
    int lane = threadIdx.x & 63;
    int wid  = threadIdx.x >> 6;
    for (int off = 32; off > 0; off >>= 1) acc += __shfl_down(acc, off);
    if (lane == 0) wsum[wid] = acc;
    __syncthreads();
    if (threadIdx.x == 0) {
        float t = 0.0f;
        for (int w = 0; w < 16; ++w) t += wsum[w];
        out[0] = t;
    }
}

extern "C" void kernel_launch(void* const* d_in, const int* in_sizes, int n_in,
                              void* d_out, int out_size, void* d_ws, size_t ws_size,
                              hipStream_t stream) {
    const float* outp  = (const float*)d_in[0];   // [B,16] logits
    const float* score = (const float*)d_in[1];   // [B]
    float* out = (float*)d_out;

    int B  = in_sizes[1];
    int nb = (B + TPB - 1) / TPB;

    float* bpart = (float*)d_ws;

    k_fused<<<nb, TPB, 0, stream>>>(outp, score, bpart, B);
    k2_sum<<<1, 1024, 0, stream>>>(bpart, nb, out);
}